// Round 1
// baseline (1804.632 us; speedup 1.0000x reference)
//
#include <hip/hip_runtime.h>
#include <hip/hip_bf16.h>
#include <stdint.h>

#define M_TOTAL 8192
#define K_TOTAL 4096
#define N_TOTAL 16384
#define BM 128
#define BN 128
#define BK 64
#define KTILES (K_TOTAL / BK)

typedef __bf16 bf16x8 __attribute__((ext_vector_type(8)));
typedef float f32x4 __attribute__((ext_vector_type(4)));
typedef unsigned short u16;
typedef u16 u16x8 __attribute__((ext_vector_type(8)));

static __device__ __forceinline__ u16 f2bf(float f) {
    unsigned int u = __builtin_bit_cast(unsigned int, f);
    u = (u + 0x7fffu + ((u >> 16) & 1u)) >> 16;   // round-to-nearest-even
    return (u16)u;
}

static __device__ __forceinline__ void async16(const void* g, void* l) {
    __builtin_amdgcn_global_load_lds((const __attribute__((address_space(1))) unsigned int*)g,
                                     (__attribute__((address_space(3))) unsigned int*)l,
                                     16, 0, 0);
}

// ---------------- conversion kernels ----------------

__global__ __launch_bounds__(256) void cvt_x_kernel(const float* __restrict__ x, u16* __restrict__ xb) {
    size_t i = ((size_t)blockIdx.x * 256 + threadIdx.x) * 8;
    const float4* s = reinterpret_cast<const float4*>(x + i);
    float4 a = s[0], b = s[1];
    u16x8 v;
    v[0] = f2bf(a.x); v[1] = f2bf(a.y); v[2] = f2bf(a.z); v[3] = f2bf(a.w);
    v[4] = f2bf(b.x); v[5] = f2bf(b.y); v[6] = f2bf(b.z); v[7] = f2bf(b.w);
    *reinterpret_cast<u16x8*>(xb + i) = v;
}

__global__ __launch_bounds__(256) void cvt_w_kernel(const int* __restrict__ w, u16* __restrict__ wb) {
    size_t i = ((size_t)blockIdx.x * 256 + threadIdx.x) * 8;
    const int4* s = reinterpret_cast<const int4*>(w + i);
    int4 a = s[0], b = s[1];
    u16x8 v;
    v[0] = f2bf((float)a.x); v[1] = f2bf((float)a.y); v[2] = f2bf((float)a.z); v[3] = f2bf((float)a.w);
    v[4] = f2bf((float)b.x); v[5] = f2bf((float)b.y); v[6] = f2bf((float)b.z); v[7] = f2bf((float)b.w);
    *reinterpret_cast<u16x8*>(wb + i) = v;
}

// ---------------- main GEMM ----------------
// A: Xb [M][K] bf16 row-major. B: Wb [N][K] bf16 row-major (i.e. B^T form).
// out[m][n] = scale[n] * sum_k A[m][k]*B[n][k]
// 128x128 tile, BK=64, 4 waves (2x2), each wave 64x64 via 4x4 frags of 16x16x32.
// LDS: A tile 16KB @0, B tile 16KB @16384. Swizzle: byte_in_row ^= ((row&7)<<4),
// applied on the GLOBAL source during global_load_lds staging (linear LDS dest)
// and on the ds_read address (both-sides rule).

__global__ __launch_bounds__(256) void gemm_kernel(const u16* __restrict__ A,
                                                   const u16* __restrict__ B,
                                                   const float* __restrict__ scale,
                                                   float* __restrict__ out) {
    __shared__ __align__(16) u16 lbuf[16384];   // 32 KB
    const int tid  = threadIdx.x;
    const int lane = tid & 63;
    const int wave = tid >> 6;

    // panel swizzle: 16 panels of 512 blocks (8 n-tiles x 64 m-tiles)
    int bid    = blockIdx.x;
    int panel  = bid >> 9;
    int within = bid & 511;
    int mt = within >> 3;
    int nt = (panel << 3) | (within & 7);
    int m0 = mt * BM, n0 = nt * BN;

    // staging: per issue i (0..3): lds byte = i*4096 + tid*16 (linear);
    // that byte belongs to row r = i*32 + (tid>>3), lin col (tid&7)*16;
    // fetch from swizzled global col so LDS holds swizzled data.
    int srow = tid >> 3;                                  // 0..31
    int scol = ((tid & 7) << 4) ^ ((srow & 7) << 4);      // swizzled byte col in 128B row
    const char* aptr = (const char*)(A + (size_t)(m0 + srow) * K_TOTAL) + scol;
    const char* bptr = (const char*)(B + (size_t)(n0 + srow) * K_TOTAL) + scol;
    char* lds = (char*)lbuf;
    const size_t rowstep = (size_t)32 * K_TOTAL * 2;      // 32 rows, bytes

    // fragment read addressing
    int swz   = (lane & 7) << 4;
    int fc    = (lane >> 4) << 4;                         // 0,16,32,48 bytes (k-group)
    int a_base = ((wave >> 1) * 64 + (lane & 15)) * 128;
    int b_base = 16384 + ((wave & 1) * 64 + (lane & 15)) * 128;

    f32x4 acc[4][4];
    #pragma unroll
    for (int mi = 0; mi < 4; ++mi)
        #pragma unroll
        for (int ni = 0; ni < 4; ++ni)
            acc[mi][ni] = (f32x4){0.f, 0.f, 0.f, 0.f};

    for (int kt = 0; kt < KTILES; ++kt) {
        #pragma unroll
        for (int i = 0; i < 4; ++i) {
            async16(aptr + i * rowstep, lds + i * 4096 + tid * 16);
            async16(bptr + i * rowstep, lds + 16384 + i * 4096 + tid * 16);
        }
        aptr += BK * 2;
        bptr += BK * 2;
        __syncthreads();   // compiler emits vmcnt(0) drain before barrier

        bf16x8 af[4][2], bfr[4][2];
        #pragma unroll
        for (int mi = 0; mi < 4; ++mi) {
            af[mi][0] = *reinterpret_cast<const bf16x8*>(lds + a_base + mi * 2048 + (fc ^ swz));
            af[mi][1] = *reinterpret_cast<const bf16x8*>(lds + a_base + mi * 2048 + ((fc + 64) ^ swz));
        }
        #pragma unroll
        for (int ni = 0; ni < 4; ++ni) {
            bfr[ni][0] = *reinterpret_cast<const bf16x8*>(lds + b_base + ni * 2048 + (fc ^ swz));
            bfr[ni][1] = *reinterpret_cast<const bf16x8*>(lds + b_base + ni * 2048 + ((fc + 64) ^ swz));
        }
        #pragma unroll
        for (int mi = 0; mi < 4; ++mi)
            #pragma unroll
            for (int ni = 0; ni < 4; ++ni) {
                acc[mi][ni] = __builtin_amdgcn_mfma_f32_16x16x32_bf16(af[mi][0], bfr[ni][0], acc[mi][ni], 0, 0, 0);
                acc[mi][ni] = __builtin_amdgcn_mfma_f32_16x16x32_bf16(af[mi][1], bfr[ni][1], acc[mi][ni], 0, 0, 0);
            }
        __syncthreads();
    }

    // epilogue: D row=(lane>>4)*4+j, col=lane&15 (verified C/D map); scale per col
    int col0 = n0 + (wave & 1) * 64 + (lane & 15);
    int row0 = m0 + (wave >> 1) * 64 + ((lane >> 4) << 2);
    #pragma unroll
    for (int ni = 0; ni < 4; ++ni) {
        float sc = scale[col0 + ni * 16];
        #pragma unroll
        for (int mi = 0; mi < 4; ++mi) {
            #pragma unroll
            for (int j = 0; j < 4; ++j) {
                out[(size_t)(row0 + mi * 16 + j) * N_TOTAL + (col0 + ni * 16)] = acc[mi][ni][j] * sc;
            }
        }
    }
}

// ---------------- fallback (insurance if ws too small) ----------------

__global__ __launch_bounds__(256) void naive_kernel(const float* __restrict__ x, const int* __restrict__ w,
                                                    const float* __restrict__ scale, float* __restrict__ out) {
    int n = blockIdx.x * 256 + threadIdx.x;
    int m = blockIdx.y;
    const float* xr = x + (size_t)m * K_TOTAL;
    const int*   wr = w + (size_t)n * K_TOTAL;
    float acc = 0.f;
    for (int k = 0; k < K_TOTAL; k += 4) {
        float4 xv = *(const float4*)(xr + k);
        int4   wv = *(const int4*)(wr + k);
        acc += xv.x * (float)wv.x + xv.y * (float)wv.y + xv.z * (float)wv.z + xv.w * (float)wv.w;
    }
    out[(size_t)m * N_TOTAL + n] = acc * scale[n];
}

extern "C" void kernel_launch(void* const* d_in, const int* in_sizes, int n_in,
                              void* d_out, int out_size, void* d_ws, size_t ws_size,
                              hipStream_t stream) {
    const float* x     = (const float*)d_in[0];
    const int*   w     = (const int*)d_in[1];
    const float* scale = (const float*)d_in[2];
    float* out = (float*)d_out;

    const size_t xb_bytes = (size_t)M_TOTAL * K_TOTAL * 2;
    const size_t wb_bytes = (size_t)N_TOTAL * K_TOTAL * 2;

    if (ws_size >= xb_bytes + wb_bytes) {
        u16* xb = (u16*)d_ws;
        u16* wb = (u16*)((char*)d_ws + xb_bytes);
        cvt_x_kernel<<<(M_TOTAL * K_TOTAL) / (256 * 8), 256, 0, stream>>>(x, xb);
        cvt_w_kernel<<<(N_TOTAL * K_TOTAL) / (256 * 8), 256, 0, stream>>>(w, wb);
        gemm_kernel<<<(M_TOTAL / BM) * (N_TOTAL / BN), 256, 0, stream>>>(xb, wb, scale, out);
    } else {
        dim3 g(N_TOTAL / 256, M_TOTAL);
        naive_kernel<<<g, 256, 0, stream>>>(x, w, scale, out);
    }
}

// Round 2
// 1579.534 us; speedup vs baseline: 1.1425x; 1.1425x over previous
//
#include <hip/hip_runtime.h>
#include <hip/hip_bf16.h>
#include <stdint.h>

#define M_TOTAL 8192
#define K_TOTAL 4096
#define N_TOTAL 16384
#define KB_ROW  (K_TOTAL * 2)          // bytes per row of A/B (bf16)
#define BM 256
#define BN 256
#define BK 64
#define KTILES (K_TOTAL / BK)          // 64
#define NITER  (KTILES / 2)            // 32
#define LDS_BUF 65536                  // one K-tile buffer: A 32KB + B 32KB
#define B_OFF   32768

typedef __bf16 bf16x8 __attribute__((ext_vector_type(8)));
typedef float f32x4 __attribute__((ext_vector_type(4)));
typedef unsigned short u16;
typedef u16 u16x8 __attribute__((ext_vector_type(8)));

static __device__ __forceinline__ u16 f2bf(float f) {
    unsigned int u = __builtin_bit_cast(unsigned int, f);
    u = (u + 0x7fffu + ((u >> 16) & 1u)) >> 16;   // RNE
    return (u16)u;
}

static __device__ __forceinline__ void async16(const void* g, void* l) {
    __builtin_amdgcn_global_load_lds((const __attribute__((address_space(1))) unsigned int*)g,
                                     (__attribute__((address_space(3))) unsigned int*)l,
                                     16, 0, 0);
}

// ---------------- conversion kernels ----------------

__global__ __launch_bounds__(256) void cvt_x_kernel(const float* __restrict__ x, u16* __restrict__ xb) {
    size_t i = ((size_t)blockIdx.x * 256 + threadIdx.x) * 8;
    const float4* s = reinterpret_cast<const float4*>(x + i);
    float4 a = s[0], b = s[1];
    u16x8 v;
    v[0] = f2bf(a.x); v[1] = f2bf(a.y); v[2] = f2bf(a.z); v[3] = f2bf(a.w);
    v[4] = f2bf(b.x); v[5] = f2bf(b.y); v[6] = f2bf(b.z); v[7] = f2bf(b.w);
    *reinterpret_cast<u16x8*>(xb + i) = v;
}

__global__ __launch_bounds__(256) void cvt_w_kernel(const int* __restrict__ w, u16* __restrict__ wb) {
    size_t i = ((size_t)blockIdx.x * 256 + threadIdx.x) * 8;
    const int4* s = reinterpret_cast<const int4*>(w + i);
    int4 a = s[0], b = s[1];
    u16x8 v;
    v[0] = f2bf((float)a.x); v[1] = f2bf((float)a.y); v[2] = f2bf((float)a.z); v[3] = f2bf((float)a.w);
    v[4] = f2bf((float)b.x); v[5] = f2bf((float)b.y); v[6] = f2bf((float)b.z); v[7] = f2bf((float)b.w);
    *reinterpret_cast<u16x8*>(wb + i) = v;
}

// ---------------- 256x256 8-phase GEMM ----------------
// A: Xb [8192][4096] bf16, B: Wb [16384][4096] bf16 (B^T form).
// 8 waves (2M x 4N), wave tile 128x64, frag 16x16x32, BK=64 (2 k-slices).
// LDS 128KB: buf d at d*65536, A [0,32768), B [32768,65536), 128B rows,
// XOR swizzle byte^=((row&7)<<4) held in LDS (linear dest + pre-swizzled
// global source), same XOR on frag reads (round-1 verified, 0 conflicts).
// Phase schedule per iteration (tiles T0=2i in buf0, T1=2i+1 in buf1):
//  P1 rd A0,B0(buf0)  stg B-h0(T1,buf1)   mfma Q00
//  P2 rd A1(buf0)     stg B-h1(T1,buf1)   mfma Q10
//  P3 rd B1(buf0)     stg A-h0(T0+2,buf0) mfma Q01
//  P4                 stg A-h1(T0+2,buf0) vmcnt(4)  mfma Q11
//  P5 rd A0,B0(buf1)  stg B-h0(T0+2,buf0) mfma Q00
//  P6 rd A1(buf1)     stg B-h1(T0+2,buf0) mfma Q10
//  P7 rd B1(buf1)     stg A-h0(T0+3,buf1) mfma Q01
//  P8                 stg A-h1(T0+3,buf1) vmcnt(4)  mfma Q11
// Every staged write is >=2 barriers after the last read of its region;
// vmcnt(4) leaves exactly the 2 newest half-tiles (4 loads) in flight.

#define BAR() { asm volatile("" ::: "memory"); __builtin_amdgcn_s_barrier(); asm volatile("" ::: "memory"); }
#define VMC4() asm volatile("s_waitcnt vmcnt(4)" ::: "memory")
#define VMC0() asm volatile("s_waitcnt vmcnt(0)" ::: "memory")

#define DS_A(dst, dOff, g) { _Pragma("unroll") \
  for (int mi = 0; mi < 4; ++mi) { \
    dst[mi][0] = *(const bf16x8*)(aR + (dOff) + (g)*8192 + mi*2048 + c0); \
    dst[mi][1] = *(const bf16x8*)(aR + (dOff) + (g)*8192 + mi*2048 + c1); } }

#define DS_B(dst, dOff, g) { _Pragma("unroll") \
  for (int ni = 0; ni < 2; ++ni) { \
    dst[ni][0] = *(const bf16x8*)(bR + (dOff) + (g)*4096 + ni*2048 + c0); \
    dst[ni][1] = *(const bf16x8*)(bR + (dOff) + (g)*4096 + ni*2048 + c1); } }

#define MMA_Q(ga, gb, Aa, Bb) { _Pragma("unroll") \
  for (int mi = 0; mi < 4; ++mi) { _Pragma("unroll") \
    for (int ni = 0; ni < 2; ++ni) { \
      acc[(ga)*4+mi][(gb)*2+ni] = __builtin_amdgcn_mfma_f32_16x16x32_bf16(Aa[mi][0], Bb[ni][0], acc[(ga)*4+mi][(gb)*2+ni], 0, 0, 0); \
      acc[(ga)*4+mi][(gb)*2+ni] = __builtin_amdgcn_mfma_f32_16x16x32_bf16(Aa[mi][1], Bb[ni][1], acc[(ga)*4+mi][(gb)*2+ni], 0, 0, 0); } } }

#define STG_A(t, h, dOff) { \
  async16(aG + (size_t)((h)*128)*KB_ROW + (t)*128, ldsc + (dOff) + (h)*16384 + tid*16); \
  async16(aG + (size_t)((h)*128 + 64)*KB_ROW + (t)*128, ldsc + (dOff) + (h)*16384 + 8192 + tid*16); }

#define STG_B(t, h, dOff) { \
  async16(bG + (size_t)((h)*128)*KB_ROW + (t)*128, ldsc + (dOff) + B_OFF + (h)*16384 + tid*16); \
  async16(bG + (size_t)((h)*128 + 64)*KB_ROW + (t)*128, ldsc + (dOff) + B_OFF + (h)*16384 + 8192 + tid*16); }

__global__ __launch_bounds__(512, 2) void gemm256_kernel(const u16* __restrict__ A,
                                                         const u16* __restrict__ B,
                                                         const float* __restrict__ scale,
                                                         float* __restrict__ out) {
    extern __shared__ char ldsc[];
    const int tid  = threadIdx.x;
    const int lane = tid & 63;
    const int wave = tid >> 6;
    const int wm = wave >> 2;          // 0..1
    const int wn = wave & 3;           // 0..3

    // XCD-aware bijective swizzle: 2048 blocks, 8 XCDs, 256-block chunks.
    // Within a chunk mt varies fastest -> 32 co-resident blocks share one
    // 2MB B-panel (L2-resident) and stream A.
    int orig = blockIdx.x;
    int swzid = (orig & 7) * 256 + (orig >> 3);
    int mt = swzid & 31;
    int nt = swzid >> 5;
    int m0 = mt * BM, n0 = nt * BN;

    // staging addresses (pre-swizzled global source, linear LDS dest)
    int srow = tid >> 3;                                   // 0..63
    int scol = ((tid & 7) << 4) ^ ((srow & 7) << 4);
    const char* aG = (const char*)A + (size_t)(m0 + srow) * KB_ROW + scol;
    const char* bG = (const char*)B + (size_t)(n0 + srow) * KB_ROW + scol;

    // fragment read addressing (swizzled)
    int klane = (lane >> 4) << 4;                          // 0,16,32,48
    int swz   = (lane & 7) << 4;
    int c0 = klane ^ swz;
    int c1 = (64 + klane) ^ swz;
    const char* aR = ldsc + (wm * 128 + (lane & 15)) * 128;
    const char* bR = ldsc + B_OFF + (wn * 64 + (lane & 15)) * 128;

    f32x4 acc[8][4];
    #pragma unroll
    for (int mi = 0; mi < 8; ++mi)
        #pragma unroll
        for (int ni = 0; ni < 4; ++ni)
            acc[mi][ni] = (f32x4){0.f, 0.f, 0.f, 0.f};

    bf16x8 a0[4][2], a1[4][2], b0[2][2], b1[2][2];

    // prologue: tile0 -> buf0 (all 4 halves), tile1 A-halves -> buf1
    STG_A(0, 0, 0); STG_A(0, 1, 0); STG_B(0, 0, 0); STG_B(0, 1, 0);
    STG_A(1, 0, LDS_BUF); STG_A(1, 1, LDS_BUF);
    VMC4();                 // tile0's 8 loads landed; tile1-A (4) may fly
    BAR();

    for (int i = 0; i < NITER; ++i) {
        const int t1 = 2 * i + 1, t2 = 2 * i + 2, t3 = 2 * i + 3;
        const bool has = (t2 < KTILES);
        // P1
        DS_A(a0, 0, 0); DS_B(b0, 0, 0);
        STG_B(t1, 0, LDS_BUF);
        BAR();
        __builtin_amdgcn_s_setprio(1); MMA_Q(0, 0, a0, b0); __builtin_amdgcn_s_setprio(0);
        BAR();
        // P2
        DS_A(a1, 0, 1);
        STG_B(t1, 1, LDS_BUF);
        BAR();
        __builtin_amdgcn_s_setprio(1); MMA_Q(1, 0, a1, b0); __builtin_amdgcn_s_setprio(0);
        BAR();
        // P3
        DS_B(b1, 0, 1);
        if (has) STG_A(t2, 0, 0);
        BAR();
        __builtin_amdgcn_s_setprio(1); MMA_Q(0, 1, a0, b1); __builtin_amdgcn_s_setprio(0);
        BAR();
        // P4
        if (has) { STG_A(t2, 1, 0); VMC4(); } else { VMC0(); }
        BAR();
        __builtin_amdgcn_s_setprio(1); MMA_Q(1, 1, a1, b1); __builtin_amdgcn_s_setprio(0);
        BAR();
        // P5
        DS_A(a0, LDS_BUF, 0); DS_B(b0, LDS_BUF, 0);
        if (has) STG_B(t2, 0, 0);
        BAR();
        __builtin_amdgcn_s_setprio(1); MMA_Q(0, 0, a0, b0); __builtin_amdgcn_s_setprio(0);
        BAR();
        // P6
        DS_A(a1, LDS_BUF, 1);
        if (has) STG_B(t2, 1, 0);
        BAR();
        __builtin_amdgcn_s_setprio(1); MMA_Q(1, 0, a1, b0); __builtin_amdgcn_s_setprio(0);
        BAR();
        // P7
        DS_B(b1, LDS_BUF, 1);
        if (has) STG_A(t3, 0, LDS_BUF);
        BAR();
        __builtin_amdgcn_s_setprio(1); MMA_Q(0, 1, a0, b1); __builtin_amdgcn_s_setprio(0);
        BAR();
        // P8
        if (has) { STG_A(t3, 1, LDS_BUF); VMC4(); }
        BAR();
        __builtin_amdgcn_s_setprio(1); MMA_Q(1, 1, a1, b1); __builtin_amdgcn_s_setprio(0);
        BAR();
    }

    // epilogue: D row=(lane>>4)*4+j, col=lane&15; scale per output col
    int col0 = n0 + wn * 64 + (lane & 15);
    int row0 = m0 + wm * 128 + ((lane >> 4) << 2);
    #pragma unroll
    for (int ni = 0; ni < 4; ++ni) {
        float sc = scale[col0 + ni * 16];
        #pragma unroll
        for (int mi = 0; mi < 8; ++mi) {
            #pragma unroll
            for (int j = 0; j < 4; ++j) {
                out[(size_t)(row0 + mi * 16 + j) * N_TOTAL + (col0 + ni * 16)] = acc[mi][ni][j] * sc;
            }
        }
    }
}

// ---------------- fallback ----------------

__global__ __launch_bounds__(256) void naive_kernel(const float* __restrict__ x, const int* __restrict__ w,
                                                    const float* __restrict__ scale, float* __restrict__ out) {
    int n = blockIdx.x * 256 + threadIdx.x;
    int m = blockIdx.y;
    const float* xr = x + (size_t)m * K_TOTAL;
    const int*   wr = w + (size_t)n * K_TOTAL;
    float acc = 0.f;
    for (int k = 0; k < K_TOTAL; k += 4) {
        float4 xv = *(const float4*)(xr + k);
        int4   wv = *(const int4*)(wr + k);
        acc += xv.x * (float)wv.x + xv.y * (float)wv.y + xv.z * (float)wv.z + xv.w * (float)wv.w;
    }
    out[(size_t)m * N_TOTAL + n] = acc * scale[n];
}

extern "C" void kernel_launch(void* const* d_in, const int* in_sizes, int n_in,
                              void* d_out, int out_size, void* d_ws, size_t ws_size,
                              hipStream_t stream) {
    const float* x     = (const float*)d_in[0];
    const int*   w     = (const int*)d_in[1];
    const float* scale = (const float*)d_in[2];
    float* out = (float*)d_out;

    const size_t xb_bytes = (size_t)M_TOTAL * K_TOTAL * 2;
    const size_t wb_bytes = (size_t)N_TOTAL * K_TOTAL * 2;

    if (ws_size >= xb_bytes + wb_bytes) {
        u16* xb = (u16*)d_ws;
        u16* wb = (u16*)((char*)d_ws + xb_bytes);
        static bool attr_set = false;
        if (!attr_set) {
            (void)hipFuncSetAttribute((const void*)gemm256_kernel,
                                      hipFuncAttributeMaxDynamicSharedMemorySize, 131072);
            attr_set = true;
        }
        cvt_x_kernel<<<(M_TOTAL * K_TOTAL) / (256 * 8), 256, 0, stream>>>(x, xb);
        cvt_w_kernel<<<(N_TOTAL * K_TOTAL) / (256 * 8), 256, 0, stream>>>(w, wb);
        gemm256_kernel<<<(M_TOTAL / BM) * (N_TOTAL / BN), 512, 131072, stream>>>(xb, wb, scale, out);
    } else {
        dim3 g(N_TOTAL / 256, M_TOTAL);
        naive_kernel<<<g, 256, 0, stream>>>(x, w, scale, out);
    }
}

// Round 3
// 1450.594 us; speedup vs baseline: 1.2441x; 1.0889x over previous
//
#include <hip/hip_runtime.h>
#include <hip/hip_bf16.h>
#include <stdint.h>

#define M_TOTAL 8192
#define K_TOTAL 4096
#define N_TOTAL 16384
#define KB_ROW  (K_TOTAL * 2)          // bytes per row of A/B (bf16)
#define BM 256
#define BN 256
#define BK 64
#define KTILES (K_TOTAL / BK)          // 64
#define NITER  (KTILES / 2)            // 32
#define LDS_BUF 65536                  // one K-tile buffer: A 32KB + B 32KB
#define B_OFF   32768

typedef __bf16 bf16x8 __attribute__((ext_vector_type(8)));
typedef float f32x4 __attribute__((ext_vector_type(4)));
typedef unsigned short u16;
typedef u16 u16x8 __attribute__((ext_vector_type(8)));

static __device__ __forceinline__ u16 f2bf(float f) {
    unsigned int u = __builtin_bit_cast(unsigned int, f);
    u = (u + 0x7fffu + ((u >> 16) & 1u)) >> 16;   // RNE
    return (u16)u;
}

static __device__ __forceinline__ void async16(const void* g, void* l) {
    __builtin_amdgcn_global_load_lds((const __attribute__((address_space(1))) unsigned int*)g,
                                     (__attribute__((address_space(3))) unsigned int*)l,
                                     16, 0, 0);
}

// ---------------- conversion kernels ----------------

__global__ __launch_bounds__(256) void cvt_x_kernel(const float* __restrict__ x, u16* __restrict__ xb) {
    size_t i = ((size_t)blockIdx.x * 256 + threadIdx.x) * 8;
    const float4* s = reinterpret_cast<const float4*>(x + i);
    float4 a = s[0], b = s[1];
    u16x8 v;
    v[0] = f2bf(a.x); v[1] = f2bf(a.y); v[2] = f2bf(a.z); v[3] = f2bf(a.w);
    v[4] = f2bf(b.x); v[5] = f2bf(b.y); v[6] = f2bf(b.z); v[7] = f2bf(b.w);
    *reinterpret_cast<u16x8*>(xb + i) = v;
}

__global__ __launch_bounds__(256) void cvt_w_kernel(const int* __restrict__ w, u16* __restrict__ wb) {
    size_t i = ((size_t)blockIdx.x * 256 + threadIdx.x) * 8;
    const int4* s = reinterpret_cast<const int4*>(w + i);
    int4 a = s[0], b = s[1];
    u16x8 v;
    v[0] = f2bf((float)a.x); v[1] = f2bf((float)a.y); v[2] = f2bf((float)a.z); v[3] = f2bf((float)a.w);
    v[4] = f2bf((float)b.x); v[5] = f2bf((float)b.y); v[6] = f2bf((float)b.z); v[7] = f2bf((float)b.w);
    *reinterpret_cast<u16x8*>(wb + i) = v;
}

// ---------------- 256x256 8-phase GEMM, deep-prefetch schedule ----------------
// Staging: full-tile stages at earliest-legal phases:
//   P3: A(T+2)->buf0 (A region free after P2's last A read)
//   P4: B(T+2)->buf0 (free after P3's B read)
//   P7: A(T+3)->buf1 (free after P6)
//   P8: B(T+3)->buf1 (free after P7)
// Waits: vmcnt(8) at P4/P8 AFTER the MFMA cluster -> 8 loads (4 half-tiles)
// in flight; every staged load has 4-5 phases of flight before its drain.
// Barriers: leading+trailing on read-phases; P4/P8 need only the trailing one.

#define BAR()   { asm volatile("" ::: "memory"); __builtin_amdgcn_s_barrier(); asm volatile("" ::: "memory"); }
#define LGKM0() asm volatile("s_waitcnt lgkmcnt(0)" ::: "memory")
#define VMC8()  asm volatile("s_waitcnt vmcnt(8)" ::: "memory")
#define VMC0()  asm volatile("s_waitcnt vmcnt(0)" ::: "memory")
#define PRIO1() __builtin_amdgcn_s_setprio(1)
#define PRIO0() __builtin_amdgcn_s_setprio(0)

#define DS_A(dst, dOff, g) { _Pragma("unroll") \
  for (int mi = 0; mi < 4; ++mi) { \
    dst[mi][0] = *(const bf16x8*)(aR + (dOff) + (g)*8192 + mi*2048 + c0); \
    dst[mi][1] = *(const bf16x8*)(aR + (dOff) + (g)*8192 + mi*2048 + c1); } }

#define DS_B(dst, dOff, g) { _Pragma("unroll") \
  for (int ni = 0; ni < 2; ++ni) { \
    dst[ni][0] = *(const bf16x8*)(bR + (dOff) + (g)*4096 + ni*2048 + c0); \
    dst[ni][1] = *(const bf16x8*)(bR + (dOff) + (g)*4096 + ni*2048 + c1); } }

// two k-slice passes: 8 independent MFMAs, then 8 depending at distance 8
#define MMA_Q(ga, gb, Aa, Bb) { \
  _Pragma("unroll") \
  for (int mi = 0; mi < 4; ++mi) { _Pragma("unroll") \
    for (int ni = 0; ni < 2; ++ni) \
      acc[(ga)*4+mi][(gb)*2+ni] = __builtin_amdgcn_mfma_f32_16x16x32_bf16(Aa[mi][0], Bb[ni][0], acc[(ga)*4+mi][(gb)*2+ni], 0, 0, 0); } \
  _Pragma("unroll") \
  for (int mi = 0; mi < 4; ++mi) { _Pragma("unroll") \
    for (int ni = 0; ni < 2; ++ni) \
      acc[(ga)*4+mi][(gb)*2+ni] = __builtin_amdgcn_mfma_f32_16x16x32_bf16(Aa[mi][1], Bb[ni][1], acc[(ga)*4+mi][(gb)*2+ni], 0, 0, 0); } }

#define STG_FULL_A(t, dOff) { _Pragma("unroll") \
  for (int c = 0; c < 4; ++c) \
    async16(aG + (size_t)(64*c)*KB_ROW + (t)*128, ldsc + (dOff) + c*8192 + tid*16); }

#define STG_FULL_B(t, dOff) { _Pragma("unroll") \
  for (int c = 0; c < 4; ++c) \
    async16(bG + (size_t)(64*c)*KB_ROW + (t)*128, ldsc + (dOff) + B_OFF + c*8192 + tid*16); }

__global__ __launch_bounds__(512, 2) void gemm256_kernel(const u16* __restrict__ A,
                                                         const u16* __restrict__ B,
                                                         const float* __restrict__ scale,
                                                         float* __restrict__ out) {
    extern __shared__ char ldsc[];
    const int tid  = threadIdx.x;
    const int lane = tid & 63;
    const int wave = tid >> 6;
    const int wm = wave >> 2;          // 0..1
    const int wn = wave & 3;           // 0..3

    // XCD-aware bijective swizzle (2048 blocks, 8 XCDs, 256-block chunks);
    // mt fastest within chunk -> 32 co-resident blocks/XCD share one B-panel.
    int orig = blockIdx.x;
    int swzid = (orig & 7) * 256 + (orig >> 3);
    int mt = swzid & 31;
    int nt = swzid >> 5;
    int m0 = mt * BM, n0 = nt * BN;

    // staging addresses (pre-swizzled global source, linear LDS dest)
    int srow = tid >> 3;                                   // 0..63
    int scol = ((tid & 7) << 4) ^ ((srow & 7) << 4);
    const char* aG = (const char*)A + (size_t)(m0 + srow) * KB_ROW + scol;
    const char* bG = (const char*)B + (size_t)(n0 + srow) * KB_ROW + scol;

    // fragment read addressing (swizzled)
    int klane = (lane >> 4) << 4;                          // 0,16,32,48
    int swz   = (lane & 7) << 4;
    int c0 = klane ^ swz;
    int c1 = (64 + klane) ^ swz;
    const char* aR = ldsc + (wm * 128 + (lane & 15)) * 128;
    const char* bR = ldsc + B_OFF + (wn * 64 + (lane & 15)) * 128;

    f32x4 acc[8][4];
    #pragma unroll
    for (int mi = 0; mi < 8; ++mi)
        #pragma unroll
        for (int ni = 0; ni < 4; ++ni)
            acc[mi][ni] = (f32x4){0.f, 0.f, 0.f, 0.f};

    bf16x8 a0[4][2], a1[4][2], b0[2][2], b1[2][2];

    // prologue: tile0 -> buf0, tile1 -> buf1 (16 loads); drain tile0 only
    STG_FULL_A(0, 0); STG_FULL_B(0, 0);
    STG_FULL_A(1, LDS_BUF); STG_FULL_B(1, LDS_BUF);
    VMC8();
    BAR();

    for (int i = 0; i < NITER - 1; ++i) {
        const int t2 = 2 * i + 2, t3 = 2 * i + 3;
        // P1
        DS_A(a0, 0, 0); DS_B(b0, 0, 0);
        BAR(); LGKM0();
        PRIO1(); MMA_Q(0, 0, a0, b0); PRIO0();
        BAR();
        // P2
        DS_A(a1, 0, 1);
        BAR(); LGKM0();
        PRIO1(); MMA_Q(1, 0, a1, b0); PRIO0();
        BAR();
        // P3
        DS_B(b1, 0, 1);
        STG_FULL_A(t2, 0);
        BAR(); LGKM0();
        PRIO1(); MMA_Q(0, 1, a0, b1); PRIO0();
        BAR();
        // P4 (no leading barrier; MFMA uses already-loaded regs)
        STG_FULL_B(t2, 0);
        PRIO1(); MMA_Q(1, 1, a1, b1); PRIO0();
        VMC8();                    // drains tile1 (A,B) -> buf1 readable
        BAR();
        // P5
        DS_A(a0, LDS_BUF, 0); DS_B(b0, LDS_BUF, 0);
        BAR(); LGKM0();
        PRIO1(); MMA_Q(0, 0, a0, b0); PRIO0();
        BAR();
        // P6
        DS_A(a1, LDS_BUF, 1);
        BAR(); LGKM0();
        PRIO1(); MMA_Q(1, 0, a1, b0); PRIO0();
        BAR();
        // P7
        DS_B(b1, LDS_BUF, 1);
        STG_FULL_A(t3, LDS_BUF);
        BAR(); LGKM0();
        PRIO1(); MMA_Q(0, 1, a0, b1); PRIO0();
        BAR();
        // P8
        STG_FULL_B(t3, LDS_BUF);
        PRIO1(); MMA_Q(1, 1, a1, b1); PRIO0();
        VMC8();                    // drains tile t2 (A,B) -> buf0 readable
        BAR();
    }

    // tail iteration (tiles KTILES-2, KTILES-1): no staging
    {
        // P1
        DS_A(a0, 0, 0); DS_B(b0, 0, 0);
        BAR(); LGKM0();
        PRIO1(); MMA_Q(0, 0, a0, b0); PRIO0();
        BAR();
        // P2
        DS_A(a1, 0, 1);
        BAR(); LGKM0();
        PRIO1(); MMA_Q(1, 0, a1, b0); PRIO0();
        BAR();
        // P3
        DS_B(b1, 0, 1);
        BAR(); LGKM0();
        PRIO1(); MMA_Q(0, 1, a0, b1); PRIO0();
        BAR();
        // P4
        PRIO1(); MMA_Q(1, 1, a1, b1); PRIO0();
        VMC0();                    // drain last tile's loads
        BAR();
        // P5
        DS_A(a0, LDS_BUF, 0); DS_B(b0, LDS_BUF, 0);
        BAR(); LGKM0();
        PRIO1(); MMA_Q(0, 0, a0, b0); PRIO0();
        BAR();
        // P6
        DS_A(a1, LDS_BUF, 1);
        BAR(); LGKM0();
        PRIO1(); MMA_Q(1, 0, a1, b0); PRIO0();
        BAR();
        // P7
        DS_B(b1, LDS_BUF, 1);
        BAR(); LGKM0();
        PRIO1(); MMA_Q(0, 1, a0, b1); PRIO0();
        BAR();
        // P8
        PRIO1(); MMA_Q(1, 1, a1, b1); PRIO0();
    }

    // epilogue: D row=(lane>>4)*4+j, col=lane&15; scale per output col
    int col0 = n0 + wn * 64 + (lane & 15);
    int row0 = m0 + wm * 128 + ((lane >> 4) << 2);
    #pragma unroll
    for (int ni = 0; ni < 4; ++ni) {
        float sc = scale[col0 + ni * 16];
        #pragma unroll
        for (int mi = 0; mi < 8; ++mi) {
            #pragma unroll
            for (int j = 0; j < 4; ++j) {
                out[(size_t)(row0 + mi * 16 + j) * N_TOTAL + (col0 + ni * 16)] = acc[mi][ni][j] * sc;
            }
        }
    }
}

// ---------------- fallback ----------------

__global__ __launch_bounds__(256) void naive_kernel(const float* __restrict__ x, const int* __restrict__ w,
                                                    const float* __restrict__ scale, float* __restrict__ out) {
    int n = blockIdx.x * 256 + threadIdx.x;
    int m = blockIdx.y;
    const float* xr = x + (size_t)m * K_TOTAL;
    const int*   wr = w + (size_t)n * K_TOTAL;
    float acc = 0.f;
    for (int k = 0; k < K_TOTAL; k += 4) {
        float4 xv = *(const float4*)(xr + k);
        int4   wv = *(const int4*)(wr + k);
        acc += xv.x * (float)wv.x + xv.y * (float)wv.y + xv.z * (float)wv.z + xv.w * (float)wv.w;
    }
    out[(size_t)m * N_TOTAL + n] = acc * scale[n];
}

extern "C" void kernel_launch(void* const* d_in, const int* in_sizes, int n_in,
                              void* d_out, int out_size, void* d_ws, size_t ws_size,
                              hipStream_t stream) {
    const float* x     = (const float*)d_in[0];
    const int*   w     = (const int*)d_in[1];
    const float* scale = (const float*)d_in[2];
    float* out = (float*)d_out;

    const size_t xb_bytes = (size_t)M_TOTAL * K_TOTAL * 2;
    const size_t wb_bytes = (size_t)N_TOTAL * K_TOTAL * 2;

    if (ws_size >= xb_bytes + wb_bytes) {
        u16* xb = (u16*)d_ws;
        u16* wb = (u16*)((char*)d_ws + xb_bytes);
        (void)hipFuncSetAttribute((const void*)gemm256_kernel,
                                  hipFuncAttributeMaxDynamicSharedMemorySize, 131072);
        cvt_x_kernel<<<(M_TOTAL * K_TOTAL) / (256 * 8), 256, 0, stream>>>(x, xb);
        cvt_w_kernel<<<(N_TOTAL * K_TOTAL) / (256 * 8), 256, 0, stream>>>(w, wb);
        gemm256_kernel<<<(M_TOTAL / BM) * (N_TOTAL / BN), 512, 131072, stream>>>(xb, wb, scale, out);
    } else {
        dim3 g(N_TOTAL / 256, M_TOTAL);
        naive_kernel<<<g, 256, 0, stream>>>(x, w, scale, out);
    }
}

// Round 4
// 1177.789 us; speedup vs baseline: 1.5322x; 1.2316x over previous
//
#include <hip/hip_runtime.h>
#include <hip/hip_bf16.h>
#include <stdint.h>

#define M_TOTAL 8192
#define K_TOTAL 4096
#define N_TOTAL 16384
#define KB_ROW  (K_TOTAL * 2)          // bytes per row of A/B (bf16)
#define BM 256
#define BN 256
#define BK 64
#define KTILES (K_TOTAL / BK)          // 64
#define LDS_BUF 65536                  // one K-tile buffer: A 32KB + B 32KB
#define B_OFF   32768

typedef __bf16 bf16x8 __attribute__((ext_vector_type(8)));
typedef float f32x4 __attribute__((ext_vector_type(4)));
typedef unsigned short u16;
typedef u16 u16x8 __attribute__((ext_vector_type(8)));

static __device__ __forceinline__ u16 f2bf(float f) {
    unsigned int u = __builtin_bit_cast(unsigned int, f);
    u = (u + 0x7fffu + ((u >> 16) & 1u)) >> 16;   // RNE
    return (u16)u;
}

static __device__ __forceinline__ void async16(const void* g, void* l) {
    __builtin_amdgcn_global_load_lds((const __attribute__((address_space(1))) unsigned int*)g,
                                     (__attribute__((address_space(3))) unsigned int*)l,
                                     16, 0, 0);
}

// ---------------- conversion kernels ----------------

__global__ __launch_bounds__(256) void cvt_x_kernel(const float* __restrict__ x, u16* __restrict__ xb) {
    size_t i = ((size_t)blockIdx.x * 256 + threadIdx.x) * 8;
    const float4* s = reinterpret_cast<const float4*>(x + i);
    float4 a = s[0], b = s[1];
    u16x8 v;
    v[0] = f2bf(a.x); v[1] = f2bf(a.y); v[2] = f2bf(a.z); v[3] = f2bf(a.w);
    v[4] = f2bf(b.x); v[5] = f2bf(b.y); v[6] = f2bf(b.z); v[7] = f2bf(b.w);
    *reinterpret_cast<u16x8*>(xb + i) = v;
}

__global__ __launch_bounds__(256) void cvt_w_kernel(const int* __restrict__ w, u16* __restrict__ wb) {
    size_t i = ((size_t)blockIdx.x * 256 + threadIdx.x) * 8;
    const int4* s = reinterpret_cast<const int4*>(w + i);
    int4 a = s[0], b = s[1];
    u16x8 v;
    v[0] = f2bf((float)a.x); v[1] = f2bf((float)a.y); v[2] = f2bf((float)a.z); v[3] = f2bf((float)a.w);
    v[4] = f2bf((float)b.x); v[5] = f2bf((float)b.y); v[6] = f2bf((float)b.z); v[7] = f2bf((float)b.w);
    *reinterpret_cast<u16x8*>(wb + i) = v;
}

// ---------------- 256x256 GEMM, 2-barrier/K-tile overlap schedule ----------------
// Per K-tile t (buf c = t&1):
//   rd b0,a0,a1 ; Q00 (a1 flies under) ; rd b1 ; Q10 ; lgkm0
//   BAR#1                       // all waves' reads of buf c retired
//   stage A(t+2),B(t+2) -> buf c
//   vmcnt(8)                    // tile t+1's 8 loads (issued at t-1) landed
//   BAR#2                       // buf ~c published for tile t+1
//   Q01,Q11 (register-only tail; overlaps other waves' next-tile reads)
// Only 2 barriers per K-tile; waves drift between BAR#2 and next BAR#1 so
// one wave's MFMA tail covers another's LDS read burst (setprio arbitration).

#define BAR()    { asm volatile("" ::: "memory"); __builtin_amdgcn_s_barrier(); asm volatile("" ::: "memory"); }
#define LGKM0()  asm volatile("s_waitcnt lgkmcnt(0)" ::: "memory")
#define VMC8()   asm volatile("s_waitcnt vmcnt(8)" ::: "memory")
#define VMC0()   asm volatile("s_waitcnt vmcnt(0)" ::: "memory")
#define PRIO1()  __builtin_amdgcn_s_setprio(1)
#define PRIO0()  __builtin_amdgcn_s_setprio(0)
#define SCHEDB() __builtin_amdgcn_sched_barrier(0)

#define DS_A(dst, dOff, g) { _Pragma("unroll") \
  for (int mi = 0; mi < 4; ++mi) { \
    dst[mi][0] = *(const bf16x8*)(aR + (dOff) + (g)*8192 + mi*2048 + c0); \
    dst[mi][1] = *(const bf16x8*)(aR + (dOff) + (g)*8192 + mi*2048 + c1); } }

#define DS_B(dst, dOff, g) { _Pragma("unroll") \
  for (int ni = 0; ni < 2; ++ni) { \
    dst[ni][0] = *(const bf16x8*)(bR + (dOff) + (g)*4096 + ni*2048 + c0); \
    dst[ni][1] = *(const bf16x8*)(bR + (dOff) + (g)*4096 + ni*2048 + c1); } }

// two k-slice passes: 8 independent MFMAs, then 8 at dep distance 8
#define MMA_Q(ga, gb, Aa, Bb) { \
  _Pragma("unroll") \
  for (int mi = 0; mi < 4; ++mi) { _Pragma("unroll") \
    for (int ni = 0; ni < 2; ++ni) \
      acc[(ga)*4+mi][(gb)*2+ni] = __builtin_amdgcn_mfma_f32_16x16x32_bf16(Aa[mi][0], Bb[ni][0], acc[(ga)*4+mi][(gb)*2+ni], 0, 0, 0); } \
  _Pragma("unroll") \
  for (int mi = 0; mi < 4; ++mi) { _Pragma("unroll") \
    for (int ni = 0; ni < 2; ++ni) \
      acc[(ga)*4+mi][(gb)*2+ni] = __builtin_amdgcn_mfma_f32_16x16x32_bf16(Aa[mi][1], Bb[ni][1], acc[(ga)*4+mi][(gb)*2+ni], 0, 0, 0); } }

#define STG_FULL_A(t, dOff) { _Pragma("unroll") \
  for (int c = 0; c < 4; ++c) \
    async16(aG + (size_t)(64*c)*KB_ROW + (t)*128, ldsc + (dOff) + c*8192 + tid*16); }

#define STG_FULL_B(t, dOff) { _Pragma("unroll") \
  for (int c = 0; c < 4; ++c) \
    async16(bG + (size_t)(64*c)*KB_ROW + (t)*128, ldsc + (dOff) + B_OFF + c*8192 + tid*16); }

__global__ __launch_bounds__(512, 2) void gemm256_kernel(const u16* __restrict__ A,
                                                         const u16* __restrict__ B,
                                                         const float* __restrict__ scale,
                                                         float* __restrict__ out) {
    extern __shared__ char ldsc[];
    const int tid  = threadIdx.x;
    const int lane = tid & 63;
    const int wave = tid >> 6;
    const int wm = wave >> 2;          // 0..1
    const int wn = wave & 3;           // 0..3

    // XCD-aware bijective swizzle (2048 blocks, 8 XCDs, 256-block chunks);
    // mt fastest within chunk -> 32 co-resident blocks/XCD share one B-panel.
    int orig = blockIdx.x;
    int swzid = (orig & 7) * 256 + (orig >> 3);
    int mt = swzid & 31;
    int nt = swzid >> 5;
    int m0 = mt * BM, n0 = nt * BN;

    // staging addresses (pre-swizzled global source, linear LDS dest)
    int srow = tid >> 3;                                   // 0..63
    int scol = ((tid & 7) << 4) ^ ((srow & 7) << 4);
    const char* aG = (const char*)A + (size_t)(m0 + srow) * KB_ROW + scol;
    const char* bG = (const char*)B + (size_t)(n0 + srow) * KB_ROW + scol;

    // fragment read addressing (swizzled)
    int klane = (lane >> 4) << 4;                          // 0,16,32,48
    int swz   = (lane & 7) << 4;
    int c0 = klane ^ swz;
    int c1 = (64 + klane) ^ swz;
    const char* aR = ldsc + (wm * 128 + (lane & 15)) * 128;
    const char* bR = ldsc + B_OFF + (wn * 64 + (lane & 15)) * 128;

    f32x4 acc[8][4];
    #pragma unroll
    for (int mi = 0; mi < 8; ++mi)
        #pragma unroll
        for (int ni = 0; ni < 4; ++ni)
            acc[mi][ni] = (f32x4){0.f, 0.f, 0.f, 0.f};

    bf16x8 a0[4][2], a1[4][2], b0[2][2], b1[2][2];

    // prologue: tile0 -> buf0, tile1 -> buf1; drain tile0, publish buf0
    STG_FULL_A(0, 0); STG_FULL_B(0, 0);
    STG_FULL_A(1, LDS_BUF); STG_FULL_B(1, LDS_BUF);
    VMC8();
    BAR();

    for (int t = 0; t < KTILES; ++t) {
        const int dOff = (t & 1) ? LDS_BUF : 0;
        // front: reads + 2 quadrants (read-ahead covers a1/b1 under MFMA)
        DS_B(b0, dOff, 0);
        DS_A(a0, dOff, 0);
        DS_A(a1, dOff, 1);
        PRIO1(); MMA_Q(0, 0, a0, b0); PRIO0();
        DS_B(b1, dOff, 1);
        PRIO1(); MMA_Q(1, 0, a1, b0); PRIO0();
        SCHEDB();
        LGKM0();                 // all tile-t LDS reads retired
        BAR();                   // bar#1: buf c free for overwrite
        const bool s2 = (t + 2 < KTILES);
        if (s2) { STG_FULL_A(t + 2, dOff); STG_FULL_B(t + 2, dOff); }
        if (t + 1 < KTILES) {
            if (s2) { VMC8(); } else { VMC0(); }
            BAR();               // bar#2: buf ~c published for tile t+1
        }
        SCHEDB();
        // tail: register-only MFMAs, overlap other waves' next-tile reads
        PRIO1(); MMA_Q(0, 1, a0, b1); MMA_Q(1, 1, a1, b1); PRIO0();
    }

    // epilogue: D row=(lane>>4)*4+j, col=lane&15; scale per output col
    int col0 = n0 + wn * 64 + (lane & 15);
    int row0 = m0 + wm * 128 + ((lane >> 4) << 2);
    #pragma unroll
    for (int ni = 0; ni < 4; ++ni) {
        float sc = scale[col0 + ni * 16];
        #pragma unroll
        for (int mi = 0; mi < 8; ++mi) {
            #pragma unroll
            for (int j = 0; j < 4; ++j) {
                out[(size_t)(row0 + mi * 16 + j) * N_TOTAL + (col0 + ni * 16)] = acc[mi][ni][j] * sc;
            }
        }
    }
}

// ---------------- fallback ----------------

__global__ __launch_bounds__(256) void naive_kernel(const float* __restrict__ x, const int* __restrict__ w,
                                                    const float* __restrict__ scale, float* __restrict__ out) {
    int n = blockIdx.x * 256 + threadIdx.x;
    int m = blockIdx.y;
    const float* xr = x + (size_t)m * K_TOTAL;
    const int*   wr = w + (size_t)n * K_TOTAL;
    float acc = 0.f;
    for (int k = 0; k < K_TOTAL; k += 4) {
        float4 xv = *(const float4*)(xr + k);
        int4   wv = *(const int4*)(wr + k);
        acc += xv.x * (float)wv.x + xv.y * (float)wv.y + xv.z * (float)wv.z + xv.w * (float)wv.w;
    }
    out[(size_t)m * N_TOTAL + n] = acc * scale[n];
}

extern "C" void kernel_launch(void* const* d_in, const int* in_sizes, int n_in,
                              void* d_out, int out_size, void* d_ws, size_t ws_size,
                              hipStream_t stream) {
    const float* x     = (const float*)d_in[0];
    const int*   w     = (const int*)d_in[1];
    const float* scale = (const float*)d_in[2];
    float* out = (float*)d_out;

    const size_t xb_bytes = (size_t)M_TOTAL * K_TOTAL * 2;
    const size_t wb_bytes = (size_t)N_TOTAL * K_TOTAL * 2;

    if (ws_size >= xb_bytes + wb_bytes) {
        u16* xb = (u16*)d_ws;
        u16* wb = (u16*)((char*)d_ws + xb_bytes);
        (void)hipFuncSetAttribute((const void*)gemm256_kernel,
                                  hipFuncAttributeMaxDynamicSharedMemorySize, 131072);
        cvt_x_kernel<<<(M_TOTAL * K_TOTAL) / (256 * 8), 256, 0, stream>>>(x, xb);
        cvt_w_kernel<<<(N_TOTAL * K_TOTAL) / (256 * 8), 256, 0, stream>>>(w, wb);
        gemm256_kernel<<<(M_TOTAL / BM) * (N_TOTAL / BN), 512, 131072, stream>>>(xb, wb, scale, out);
    } else {
        dim3 g(N_TOTAL / 256, M_TOTAL);
        naive_kernel<<<g, 256, 0, stream>>>(x, w, scale, out);
    }
}